// Round 1
// baseline (131.257 us; speedup 1.0000x reference)
//
#include <hip/hip_runtime.h>
#include <hip/hip_bf16.h>

#define BH 16
#define L 2048
#define S 2048
#define DD 64
#define BM 64
#define BK 64
#define LDSPAD 8
#define LDW (BK + LDSPAD)   // 72 elements -> 144B row stride, 16B aligned

typedef __attribute__((ext_vector_type(4))) float f32x4;
typedef __bf16 bf16x8 __attribute__((ext_vector_type(8)));

// ---------------------------------------------------------------------------
// Kernel A: row sums of Q (BH*L rows) and K (BH*S rows), each row = 64 floats.
// One 16-lane group per row: float4 load + 16-wide shuffle reduce.
// ---------------------------------------------------------------------------
__global__ __launch_bounds__(256) void rowsum_kernel(
    const float* __restrict__ q, const float* __restrict__ k,
    float* __restrict__ qs, float* __restrict__ ks) {
  int t = blockIdx.x * 256 + threadIdx.x;
  int row = t >> 4;
  int l16 = t & 15;
  const float* src;
  float* dst;
  if (row < BH * L) {
    src = q + (size_t)row * DD;
    dst = qs + row;
  } else {
    int r2 = row - BH * L;
    src = k + (size_t)r2 * DD;
    dst = ks + r2;
  }
  float4 v = reinterpret_cast<const float4*>(src)[l16];
  float s = v.x + v.y + v.z + v.w;
  s += __shfl_xor(s, 1);
  s += __shfl_xor(s, 2);
  s += __shfl_xor(s, 4);
  s += __shfl_xor(s, 8);
  if (l16 == 0) *dst = s;
}

// ---------------------------------------------------------------------------
// Kernel B: per-head max/min of ksum (for stable softmax).
// ---------------------------------------------------------------------------
__global__ __launch_bounds__(256) void minmax_kernel(
    const float* __restrict__ ks, float* __restrict__ kmm) {
  int bh = blockIdx.x;
  const float* p = ks + (size_t)bh * S;
  float mx = -1e30f, mn = 1e30f;
  for (int i = threadIdx.x; i < S; i += 256) {
    float v = p[i];
    mx = fmaxf(mx, v);
    mn = fminf(mn, v);
  }
#pragma unroll
  for (int off = 1; off < 64; off <<= 1) {
    mx = fmaxf(mx, __shfl_xor(mx, off));
    mn = fminf(mn, __shfl_xor(mn, off));
  }
  __shared__ float smx[4], smn[4];
  int w = threadIdx.x >> 6;
  if ((threadIdx.x & 63) == 0) { smx[w] = mx; smn[w] = mn; }
  __syncthreads();
  if (threadIdx.x == 0) {
    mx = fmaxf(fmaxf(smx[0], smx[1]), fmaxf(smx[2], smx[3]));
    mn = fminf(fminf(smn[0], smn[1]), fminf(smn[2], smn[3]));
    kmm[bh * 2] = mx;
    kmm[bh * 2 + 1] = mn;
  }
}

// ---------------------------------------------------------------------------
// Kernel C: V [bh][s][d] fp32 -> VT [bh][d][s] bf16 (so main-kernel B-fragment
// LDS reads are contiguous b128). LDS-tiled 64x64 transpose per block.
// ---------------------------------------------------------------------------
__global__ __launch_bounds__(256) void transpose_kernel(
    const float* __restrict__ v, __hip_bfloat16* __restrict__ vt) {
  int s0 = blockIdx.x * 64;
  int bh = blockIdx.y;
  __shared__ __hip_bfloat16 tile[DD][LDW];
  int t = threadIdx.x;
  int srow = t >> 4;          // 0..15
  int d4 = (t & 15) * 4;
#pragma unroll
  for (int kk = 0; kk < 4; ++kk) {
    int s = srow + kk * 16;
    float4 val = *reinterpret_cast<const float4*>(
        v + ((size_t)(bh * S + s0 + s)) * DD + d4);
    tile[d4 + 0][s] = __float2bfloat16(val.x);
    tile[d4 + 1][s] = __float2bfloat16(val.y);
    tile[d4 + 2][s] = __float2bfloat16(val.z);
    tile[d4 + 3][s] = __float2bfloat16(val.w);
  }
  __syncthreads();
  int dd = t >> 3;            // 0..31
  int j = t & 7;
#pragma unroll
  for (int kk = 0; kk < 2; ++kk) {
    int d = dd + kk * 32;
    uint4 val = *reinterpret_cast<const uint4*>(&tile[d][j * 8]);
    *reinterpret_cast<uint4*>(vt + ((size_t)(bh * DD + d)) * S + s0 + j * 8) = val;
  }
}

// ---------------------------------------------------------------------------
// Kernel D: main. Per block: 64 L-rows of one head. K-loop over S in steps of
// 64: stage ksum chunk + VT tile, generate E=exp(a*(k-sel)) bf16 tile in LDS
// (fp32 denominator partials in registers), MFMA 16x16x32 bf16 into 16x64
// per-wave C tiles, epilogue divides by denominator.
// ---------------------------------------------------------------------------
__global__ __launch_bounds__(256) void attn_kernel(
    const __hip_bfloat16* __restrict__ vt,
    const float* __restrict__ qs, const float* __restrict__ ks,
    const float* __restrict__ kmm, float* __restrict__ out) {
  int l0 = blockIdx.x * BM;
  int bh = blockIdx.y;

  __shared__ float a_row[BM], sel_row[BM];
  __shared__ float kch[BK];
  __shared__ __hip_bfloat16 ldsE[BM][LDW];
  __shared__ __hip_bfloat16 ldsVT[DD][LDW];

  int t = threadIdx.x;
  int lane = t & 63;
  int w = t >> 6;

  if (t < BM) {
    float a = qs[(size_t)bh * L + l0 + t];
    // stable-softmax row max = a*kmax (a>0) or a*kmin (a<=0)
    float sel = (a > 0.f) ? kmm[bh * 2] : kmm[bh * 2 + 1];
    a_row[t] = a;
    sel_row[t] = sel;
  }
  __syncthreads();

  int r = t >> 2;            // E-gen row 0..63 (wave w owns rows 16w..16w+15)
  int sc = (t & 3) << 4;     // s offset within tile: 0/16/32/48
  float ar = a_row[r];
  float selr = sel_row[r];
  float dsum = 0.f;

  f32x4 acc[4];
#pragma unroll
  for (int c = 0; c < 4; ++c) acc[c] = (f32x4){0.f, 0.f, 0.f, 0.f};

  int vd = t >> 3;           // VT staging: 0..31
  int vj = t & 7;

  for (int s0 = 0; s0 < S; s0 += BK) {
    // stage ksum chunk
    if (t < BK) kch[t] = ks[(size_t)bh * S + s0 + t];
    // stage VT tile (bf16, already transposed: rows=d, cols=s)
#pragma unroll
    for (int kk = 0; kk < 2; ++kk) {
      int d = vd + kk * 32;
      uint4 val = *reinterpret_cast<const uint4*>(
          vt + ((size_t)(bh * DD + d)) * S + s0 + vj * 8);
      *reinterpret_cast<uint4*>(&ldsVT[d][vj * 8]) = val;
    }
    __syncthreads();

    // E-tile generation: 16 exps per thread, packed bf16x2 stores
#pragma unroll
    for (int jj = 0; jj < 16; jj += 2) {
      float e0 = __expf(ar * (kch[sc + jj] - selr));
      float e1 = __expf(ar * (kch[sc + jj + 1] - selr));
      dsum += e0 + e1;
      *reinterpret_cast<__hip_bfloat162*>(&ldsE[r][sc + jj]) =
          __float22bfloat162_rn(make_float2(e0, e1));
    }
    __syncthreads();

    // MFMA: wave w computes rows [16w,16w+16) x all 64 cols
#pragma unroll
    for (int kk = 0; kk < 2; ++kk) {
      int kb = kk * 32 + ((lane >> 4) << 3);
      uint4 au = *reinterpret_cast<const uint4*>(&ldsE[w * 16 + (lane & 15)][kb]);
      bf16x8 af = __builtin_bit_cast(bf16x8, au);
#pragma unroll
      for (int c = 0; c < 4; ++c) {
        uint4 bu = *reinterpret_cast<const uint4*>(&ldsVT[c * 16 + (lane & 15)][kb]);
        bf16x8 bf = __builtin_bit_cast(bf16x8, bu);
        acc[c] = __builtin_amdgcn_mfma_f32_16x16x32_bf16(af, bf, acc[c], 0, 0, 0);
      }
    }
    __syncthreads();
  }

  // denominator: row total lives in the 4 lanes of each quad (rows = lane>>2)
  float dt = dsum;
  dt += __shfl_xor(dt, 1);
  dt += __shfl_xor(dt, 2);
  int quad = lane >> 4;
  float inv[4];
#pragma unroll
  for (int i = 0; i < 4; ++i) {
    float rd = __shfl(dt, (quad << 4) + (i << 2));  // lane rl*4, rl=quad*4+i
    inv[i] = 1.0f / rd;
  }
  int colb = lane & 15;
#pragma unroll
  for (int c = 0; c < 4; ++c) {
#pragma unroll
    for (int i = 0; i < 4; ++i) {
      int row = l0 + w * 16 + quad * 4 + i;  // C layout: col=lane&15, row=quad*4+reg
      out[((size_t)(bh * L + row)) * DD + c * 16 + colb] = acc[c][i] * inv[i];
    }
  }
}

extern "C" void kernel_launch(void* const* d_in, const int* in_sizes, int n_in,
                              void* d_out, int out_size, void* d_ws, size_t ws_size,
                              hipStream_t stream) {
  const float* q = (const float*)d_in[0];
  const float* k = (const float*)d_in[1];
  const float* v = (const float*)d_in[2];
  float* out = (float*)d_out;
  float* ws = (float*)d_ws;

  float* qs = ws;                          // BH*L   = 32768 floats
  float* ks = ws + BH * L;                 // BH*S   = 32768 floats
  float* kmm = ws + BH * (L + S);          // 32 floats
  __hip_bfloat16* vt =
      (__hip_bfloat16*)(ws + BH * (L + S) + 64);  // BH*D*S bf16 = 4 MB, 16B aligned

  rowsum_kernel<<<(BH * (L + S)) / 16, 256, 0, stream>>>(q, k, qs, ks);
  minmax_kernel<<<BH, 256, 0, stream>>>(ks, kmm);
  transpose_kernel<<<dim3(S / 64, BH), 256, 0, stream>>>(v, vt);
  attn_kernel<<<dim3(L / BM, BH), 256, 0, stream>>>(vt, qs, ks, kmm, out);
}

// Round 2
// 96.837 us; speedup vs baseline: 1.3554x; 1.3554x over previous
//
#include <hip/hip_runtime.h>
#include <hip/hip_bf16.h>

#define BH 16
#define L 2048
#define S 2048
#define DD 64
#define BM 64
#define BK 64
#define LDSPAD 8
#define LDW (BK + LDSPAD)   // 72 elements -> 144B row stride, 16B aligned

typedef __attribute__((ext_vector_type(4))) float f32x4;
typedef __bf16 bf16x8 __attribute__((ext_vector_type(8)));

union FragU {
  bf16x8 f;
  __hip_bfloat162 h2[4];
};

__device__ inline __hip_bfloat162 exp2pack(float al2, float nsl2, float k0,
                                           float k1, float& d) {
  float e0 = __builtin_amdgcn_exp2f(fmaf(al2, k0, nsl2));
  float e1 = __builtin_amdgcn_exp2f(fmaf(al2, k1, nsl2));
  d += e0 + e1;
  return __float22bfloat162_rn(make_float2(e0, e1));
}

// ---------------------------------------------------------------------------
// prep: blocks [0,2048): K row sums (16 lanes per row).
//       blocks [2048,2560): V [bh][s][d] fp32 -> VT [bh][d][s] bf16 transpose.
// ---------------------------------------------------------------------------
__global__ __launch_bounds__(256) void prep_kernel(
    const float* __restrict__ k, const float* __restrict__ v,
    float* __restrict__ ks, __hip_bfloat16* __restrict__ vt) {
  __shared__ __hip_bfloat16 tile[DD][LDW];
  int t = threadIdx.x;
  if (blockIdx.x < 2048) {
    int g = blockIdx.x * 256 + t;
    int row = g >> 4;
    int l16 = g & 15;
    float4 x = reinterpret_cast<const float4*>(k + (size_t)row * DD)[l16];
    float s = x.x + x.y + x.z + x.w;
    s += __shfl_xor(s, 1);
    s += __shfl_xor(s, 2);
    s += __shfl_xor(s, 4);
    s += __shfl_xor(s, 8);
    if (l16 == 0) ks[row] = s;
  } else {
    int bid = blockIdx.x - 2048;
    int s0 = (bid & 31) * 64;
    int bh = bid >> 5;
    int srow = t >> 4;
    int d4 = (t & 15) * 4;
#pragma unroll
    for (int kk = 0; kk < 4; ++kk) {
      int s = srow + kk * 16;
      float4 val = *reinterpret_cast<const float4*>(
          v + ((size_t)(bh * S + s0 + s)) * DD + d4);
      tile[d4 + 0][s] = __float2bfloat16(val.x);
      tile[d4 + 1][s] = __float2bfloat16(val.y);
      tile[d4 + 2][s] = __float2bfloat16(val.z);
      tile[d4 + 3][s] = __float2bfloat16(val.w);
    }
    __syncthreads();
    int dd = t >> 3;
    int j = t & 7;
#pragma unroll
    for (int kk = 0; kk < 2; ++kk) {
      int d = dd + kk * 32;
      uint4 val = *reinterpret_cast<const uint4*>(&tile[d][j * 8]);
      *reinterpret_cast<uint4*>(vt + ((size_t)(bh * DD + d)) * S + s0 + j * 8) =
          val;
    }
  }
}

// ---------------------------------------------------------------------------
// attn: one block = 64 L-rows of one head. Prologue computes this block's
// qsums + per-head kmax/kmin (per-block sel is legal: it cancels in the
// softmax ratio). K-loop: E generated per-lane in A-fragment registers
// (no LDS for E), VT double-buffered in LDS with register prefetch ->
// ONE barrier per tile, global loads overlap compute.
// ---------------------------------------------------------------------------
__global__ __launch_bounds__(256) void attn_kernel(
    const float* __restrict__ q, const __hip_bfloat16* __restrict__ vt,
    const float* __restrict__ ks, float* __restrict__ out) {
  int l0 = blockIdx.x * BM;
  int bh = blockIdx.y;

  __shared__ __hip_bfloat16 ldsVT[2][DD][LDW];
  __shared__ float a_row[BM];
  __shared__ float red[16];

  int t = threadIdx.x;
  int lane = t & 63;
  int w = t >> 6;
  int m = lane & 15;
  int qd = lane >> 4;  // quad 0..3

  const __hip_bfloat16* vtb = vt + (size_t)bh * DD * S;
  const float* ksb = ks + (size_t)bh * S;

  int vd = t >> 3;  // 0..31
  int vj = t & 7;

  // --- prologue global prefetch: VT tile 0 + ksum chunk 0 (overlaps reduces)
  uint4 v0 = *reinterpret_cast<const uint4*>(vtb + (size_t)vd * S + vj * 8);
  uint4 v1 =
      *reinterpret_cast<const uint4*>(vtb + (size_t)(vd + 32) * S + vj * 8);
  float4 kA0 = *reinterpret_cast<const float4*>(ksb + qd * 8);
  float4 kA1 = *reinterpret_cast<const float4*>(ksb + qd * 8 + 4);
  float4 kB0 = *reinterpret_cast<const float4*>(ksb + 32 + qd * 8);
  float4 kB1 = *reinterpret_cast<const float4*>(ksb + 32 + qd * 8 + 4);

  // --- qsum for this block's 64 rows: 4 lanes per row
  {
    int r = t >> 2;
    int p = t & 3;
    const float* qp = q + ((size_t)(bh * L + l0 + r)) * DD + p * 16;
    float4 x0 = reinterpret_cast<const float4*>(qp)[0];
    float4 x1 = reinterpret_cast<const float4*>(qp)[1];
    float4 x2 = reinterpret_cast<const float4*>(qp)[2];
    float4 x3 = reinterpret_cast<const float4*>(qp)[3];
    float s = (x0.x + x0.y + x0.z + x0.w) + (x1.x + x1.y + x1.z + x1.w) +
              (x2.x + x2.y + x2.z + x2.w) + (x3.x + x3.y + x3.z + x3.w);
    s += __shfl_xor(s, 1);
    s += __shfl_xor(s, 2);
    if (p == 0) a_row[r] = s;
  }

  // --- per-head kmax/kmin (per-block reduction)
  {
    const float* kp = ksb + t * 8;
    float4 y0 = reinterpret_cast<const float4*>(kp)[0];
    float4 y1 = reinterpret_cast<const float4*>(kp)[1];
    float mx = fmaxf(fmaxf(fmaxf(y0.x, y0.y), fmaxf(y0.z, y0.w)),
                     fmaxf(fmaxf(y1.x, y1.y), fmaxf(y1.z, y1.w)));
    float mn = fminf(fminf(fminf(y0.x, y0.y), fminf(y0.z, y0.w)),
                     fminf(fminf(y1.x, y1.y), fminf(y1.z, y1.w)));
#pragma unroll
    for (int off = 1; off < 64; off <<= 1) {
      mx = fmaxf(mx, __shfl_xor(mx, off));
      mn = fminf(mn, __shfl_xor(mn, off));
    }
    if (lane == 0) {
      red[w] = mx;
      red[8 + w] = mn;
    }
  }
  __syncthreads();

  float kmax = fmaxf(fmaxf(red[0], red[1]), fmaxf(red[2], red[3]));
  float kmin = fminf(fminf(red[8], red[9]), fminf(red[10], red[11]));
  float ar = a_row[w * 16 + m];  // this lane's E-row coefficient
  float sel = (ar > 0.f) ? kmax : kmin;
  const float LOG2E = 1.44269504088896f;
  float al2 = ar * LOG2E;
  float nsl2 = -al2 * sel;

  float dsum = 0.f;
  f32x4 acc[4];
#pragma unroll
  for (int c = 0; c < 4; ++c) acc[c] = (f32x4){0.f, 0.f, 0.f, 0.f};

  for (int it = 0; it < 32; ++it) {
    int bufi = it & 1;
    // store prefetched VT tile
    *reinterpret_cast<uint4*>(&ldsVT[bufi][vd][vj * 8]) = v0;
    *reinterpret_cast<uint4*>(&ldsVT[bufi][vd + 32][vj * 8]) = v1;
    __syncthreads();  // the ONLY barrier per tile

    int s0n = (it < 31) ? (it + 1) * BK : 31 * BK;  // clamped prefetch addr
    v0 = *reinterpret_cast<const uint4*>(vtb + (size_t)vd * S + s0n + vj * 8);
    v1 = *reinterpret_cast<const uint4*>(vtb + (size_t)(vd + 32) * S + s0n +
                                         vj * 8);

    // E fragments in registers (A-layout: row m, k = kk*32 + qd*8 + j)
    FragU f0, f1;
    f0.h2[0] = exp2pack(al2, nsl2, kA0.x, kA0.y, dsum);
    f0.h2[1] = exp2pack(al2, nsl2, kA0.z, kA0.w, dsum);
    f0.h2[2] = exp2pack(al2, nsl2, kA1.x, kA1.y, dsum);
    f0.h2[3] = exp2pack(al2, nsl2, kA1.z, kA1.w, dsum);
    f1.h2[0] = exp2pack(al2, nsl2, kB0.x, kB0.y, dsum);
    f1.h2[1] = exp2pack(al2, nsl2, kB0.z, kB0.w, dsum);
    f1.h2[2] = exp2pack(al2, nsl2, kB1.x, kB1.y, dsum);
    f1.h2[3] = exp2pack(al2, nsl2, kB1.z, kB1.w, dsum);

    // prefetch next ksum chunk
    kA0 = *reinterpret_cast<const float4*>(ksb + s0n + qd * 8);
    kA1 = *reinterpret_cast<const float4*>(ksb + s0n + qd * 8 + 4);
    kB0 = *reinterpret_cast<const float4*>(ksb + s0n + 32 + qd * 8);
    kB1 = *reinterpret_cast<const float4*>(ksb + s0n + 32 + qd * 8 + 4);

    // MFMA: wave computes rows [w*16, w*16+16) x 64 cols
#pragma unroll
    for (int c = 0; c < 4; ++c) {
      uint4 bu0 =
          *reinterpret_cast<const uint4*>(&ldsVT[bufi][c * 16 + m][qd * 8]);
      acc[c] = __builtin_amdgcn_mfma_f32_16x16x32_bf16(
          f0.f, __builtin_bit_cast(bf16x8, bu0), acc[c], 0, 0, 0);
      uint4 bu1 = *reinterpret_cast<const uint4*>(
          &ldsVT[bufi][c * 16 + m][32 + qd * 8]);
      acc[c] = __builtin_amdgcn_mfma_f32_16x16x32_bf16(
          f1.f, __builtin_bit_cast(bf16x8, bu1), acc[c], 0, 0, 0);
    }
  }

  // row denominators: lanes {m, m+16, m+32, m+48} hold partial sums of row m
  float dt = dsum;
  dt += __shfl_xor(dt, 16);
  dt += __shfl_xor(dt, 32);
  float inv[4];
#pragma unroll
  for (int i = 0; i < 4; ++i) inv[i] = 1.0f / __shfl(dt, qd * 4 + i);

  // C layout: col = lane&15, row = quad*4 + reg
  float* ob = out + ((size_t)(bh * L + l0 + w * 16)) * DD;
#pragma unroll
  for (int c = 0; c < 4; ++c) {
#pragma unroll
    for (int i = 0; i < 4; ++i) {
      ob[(size_t)(qd * 4 + i) * DD + c * 16 + m] = acc[c][i] * inv[i];
    }
  }
}

extern "C" void kernel_launch(void* const* d_in, const int* in_sizes, int n_in,
                              void* d_out, int out_size, void* d_ws,
                              size_t ws_size, hipStream_t stream) {
  const float* q = (const float*)d_in[0];
  const float* k = (const float*)d_in[1];
  const float* v = (const float*)d_in[2];
  float* out = (float*)d_out;
  float* ws = (float*)d_ws;

  float* ks = ws;  // BH*S = 32768 floats
  __hip_bfloat16* vt = (__hip_bfloat16*)(ws + BH * S);  // BH*DD*S bf16 = 4MB

  prep_kernel<<<2048 + 512, 256, 0, stream>>>(k, v, ks, vt);
  attn_kernel<<<dim3(L / BM, BH), 256, 0, stream>>>(q, vt, ks, out);
}